// Round 2
// baseline (173.115 us; speedup 1.0000x reference)
//
#include <hip/hip_runtime.h>
#include <hip/hip_bf16.h>

#define TT  2048
#define NH  32
#define NKV 8
#define DD  128
#define KVB 64          // keys per LDS tile
#define KSTR 136        // K row stride in bf16: 272B
#define VSTR 72         // Vt row stride in bf16: 144B
#define PSTR 72         // P row stride in bf16

typedef __attribute__((ext_vector_type(8))) short  short8;
typedef __attribute__((ext_vector_type(4))) float  f32x4;

static __device__ __forceinline__ short f2bf(float x) {
  __bf16 b = (__bf16)x;                 // RNE f32->bf16
  return __builtin_bit_cast(short, b);
}
static __device__ __forceinline__ short8 cvt8(f32x4 a, f32x4 b) {
  short8 r;
  r[0]=f2bf(a[0]); r[1]=f2bf(a[1]); r[2]=f2bf(a[2]); r[3]=f2bf(a[3]);
  r[4]=f2bf(b[0]); r[5]=f2bf(b[1]); r[6]=f2bf(b[2]); r[7]=f2bf(b[3]);
  return r;
}

// Block = one kv-head x 32 Q-rows x 4 GQA heads.
// 8 waves: wave w -> head = kvh*4 + (w&3), row-group = (w>>2)*16.
// All 8 waves share K/V tiles staged in LDS (bf16; V transposed).
// T14 async staging with the ISSUE POINT AFTER QK^T so the in-flight
// registers (32 VGPRs) never co-live with the s[] score fragments --
// keeps unified VGPR+AGPR <= 128 (the __launch_bounds__(512,4) cap)
// and avoids the scratch spills seen in round 1.
// MFMA 16x16x32 bf16. A-frag: lane holds A[row=l&15][k=8*(l>>4)+i].
// B-frag: lane holds B[k=8*(l>>4)+i][col=l&15].
// C/D:    lane holds C[row=(l>>4)*4+r][col=l&15].
__global__ __launch_bounds__(512, 4) void attn_fwd(
    const float* __restrict__ Q, const float* __restrict__ K,
    const float* __restrict__ V, float* __restrict__ O,
    float* __restrict__ Mo, float* __restrict__ Lo)
{
  __shared__ __align__(16) short Kb[KVB][KSTR];     // K[j][d], bf16
  __shared__ __align__(16) short Vt[DD][VSTR];      // V transposed: Vt[d][j]
  __shared__ __align__(16) short Pl[8][16][PSTR];   // per-wave P transpose buf

  const int bid  = blockIdx.x;
  const int kvh  = bid & (NKV - 1);          // kvh == XCD id under round-robin
  const int jj   = bid >> 3;                 // 0..63
  // balanced pairing: blocks c and c+256 land on the same CU (2 blocks/CU,
  // whole grid resident). Pair heavy (q32=63-jj) with light (q32=jj-32).
  const int q32  = (jj < 32) ? (63 - jj) : (jj - 32);
  const int wv   = threadIdx.x >> 6;         // 0..7
  const int lane = threadIdx.x & 63;
  const int l15  = lane & 15;
  const int g4   = lane >> 4;
  const int head = kvh * 4 + (wv & 3);
  const int qbase = q32 * 32 + (wv >> 2) * 16;

  // K staging: row = tid>>3 (coalesced 512B runs), 16-col seg = tid&7
  const int krow = threadIdx.x >> 3;
  const int kseg = threadIdx.x & 7;
  // V staging: row = lane, d-seg = wv*16 (per-wave-uniform d -> conflict-free scatter)
  const int vrow = lane;
  const int vd0  = wv * 16;

  // ---- Q fragments: lane holds Q[qbase+(l&15)][32*ks + 8*g4 + i] ----
  short8 aq[4];
  {
    const float* qp = Q + ((size_t)(qbase + l15) * NH + head) * DD;
#pragma unroll
    for (int ks = 0; ks < 4; ++ks) {
      const float* p = qp + ks * 32 + g4 * 8;
      aq[ks] = cvt8(*reinterpret_cast<const f32x4*>(p),
                    *reinterpret_cast<const f32x4*>(p + 4));
    }
  }

  f32x4 acc[8];
#pragma unroll
  for (int i = 0; i < 8; ++i) acc[i] = (f32x4)0.0f;
  float m[4], lsum[4];
#pragma unroll
  for (int r = 0; r < 4; ++r) { m[r] = -INFINITY; lsum[r] = 0.0f; }

  // ceil((q32*32+32)/64): same for both row-groups (proof: ceil((2q+1)/4)==ceil((2q+2)/4))
  const int ntiles = (q32 * 32 + 95) >> 6;

  // incremental staging pointers (advance one 64-key tile per step)
  const size_t TSTEP = (size_t)KVB * NKV * DD;
  const float* kp = K + ((size_t)krow * NKV + kvh) * DD + kseg * 16;
  const float* vp = V + ((size_t)vrow * NKV + kvh) * DD + vd0;

  // ---- prologue: issue tile-0 staging loads ----
  f32x4 kreg[4], vreg[4];
#pragma unroll
  for (int c = 0; c < 4; ++c) {
    kreg[c] = *reinterpret_cast<const f32x4*>(kp + c * 4);
    vreg[c] = *reinterpret_cast<const f32x4*>(vp + c * 4);
  }
  kp += TSTEP; vp += TSTEP;

  for (int jt = 0; jt < ntiles; ++jt) {
    const int j0 = jt << 6;

    __syncthreads();   // all waves done reading LDS tile jt-1
    // ---- commit staged tile jt (loads were issued a full phase ago) ----
    *reinterpret_cast<short8*>(&Kb[krow][kseg * 16])     = cvt8(kreg[0], kreg[1]);
    *reinterpret_cast<short8*>(&Kb[krow][kseg * 16 + 8]) = cvt8(kreg[2], kreg[3]);
#pragma unroll
    for (int c = 0; c < 4; ++c)
#pragma unroll
      for (int i = 0; i < 4; ++i)
        Vt[vd0 + c * 4 + i][vrow] = f2bf(vreg[c][i]);
    __syncthreads();

    // ---- QK^T: S[16 x 64] as four 16-col C/D frags ----
    f32x4 s[4];
#pragma unroll
    for (int c = 0; c < 4; ++c) s[c] = (f32x4)0.0f;
    __builtin_amdgcn_s_setprio(1);
#pragma unroll
    for (int c = 0; c < 4; ++c) {
      const short* kr = &Kb[c * 16 + l15][g4 * 8];
#pragma unroll
      for (int ks = 0; ks < 4; ++ks) {
        short8 kb = *reinterpret_cast<const short8*>(kr + ks * 32);
        s[c] = __builtin_amdgcn_mfma_f32_16x16x32_bf16(aq[ks], kb, s[c], 0, 0, 0);
      }
    }
    __builtin_amdgcn_s_setprio(0);

    // ---- T14 (late issue): next tile's loads; s[] no longer needs new regs,
    //      and kreg/vreg stay live only through softmax+PV ----
    if (jt + 1 < ntiles) {
#pragma unroll
      for (int c = 0; c < 4; ++c) {
        kreg[c] = *reinterpret_cast<const f32x4*>(kp + c * 4);
        vreg[c] = *reinterpret_cast<const f32x4*>(vp + c * 4);
      }
      kp += TSTEP; vp += TSTEP;
    }

    // ---- causal mask: only the last tile can cross the diagonal ----
    if (jt == ntiles - 1) {
#pragma unroll
      for (int c = 0; c < 4; ++c)
#pragma unroll
        for (int r = 0; r < 4; ++r)
          if (j0 + c * 16 + l15 > qbase + g4 * 4 + r) s[c][r] = -1.0e10f;
    }

    // ---- online softmax over the 64-key tile ----
    float sc[4];
#pragma unroll
    for (int r = 0; r < 4; ++r) {
      float t = fmaxf(fmaxf(s[0][r], s[1][r]), fmaxf(s[2][r], s[3][r]));
      t = fmaxf(t, __shfl_xor(t, 1));
      t = fmaxf(t, __shfl_xor(t, 2));
      t = fmaxf(t, __shfl_xor(t, 4));
      t = fmaxf(t, __shfl_xor(t, 8));
      float mn = fmaxf(m[r], t);
      sc[r] = __expf(m[r] - mn);
      m[r] = mn;
      lsum[r] *= sc[r];
    }
#pragma unroll
    for (int c = 0; c < 4; ++c)
#pragma unroll
      for (int r = 0; r < 4; ++r) {
        float p = __expf(s[c][r] - m[r]);
        lsum[r] += p;
        Pl[wv][g4 * 4 + r][c * 16 + l15] = f2bf(p);
      }
    f32x4 sv; sv[0]=sc[0]; sv[1]=sc[1]; sv[2]=sc[2]; sv[3]=sc[3];
#pragma unroll
    for (int dt = 0; dt < 8; ++dt) acc[dt] = acc[dt] * sv;

    // ---- P @ V: K-dim = 64 keys, 8 d-tiles ----
    short8 pa0 = *reinterpret_cast<const short8*>(&Pl[wv][l15][g4 * 8]);
    short8 pa1 = *reinterpret_cast<const short8*>(&Pl[wv][l15][32 + g4 * 8]);
    __builtin_amdgcn_s_setprio(1);
#pragma unroll
    for (int dt = 0; dt < 8; ++dt) {
      short8 v0 = *reinterpret_cast<const short8*>(&Vt[dt * 16 + l15][g4 * 8]);
      short8 v1 = *reinterpret_cast<const short8*>(&Vt[dt * 16 + l15][32 + g4 * 8]);
      acc[dt] = __builtin_amdgcn_mfma_f32_16x16x32_bf16(pa0, v0, acc[dt], 0, 0, 0);
      acc[dt] = __builtin_amdgcn_mfma_f32_16x16x32_bf16(pa1, v1, acc[dt], 0, 0, 0);
    }
    __builtin_amdgcn_s_setprio(0);
  }

  // ---- epilogue ----
#pragma unroll
  for (int r = 0; r < 4; ++r) {
    float t = lsum[r];
    t += __shfl_xor(t, 1);
    t += __shfl_xor(t, 2);
    t += __shfl_xor(t, 4);
    t += __shfl_xor(t, 8);
    lsum[r] = t;
  }

#pragma unroll
  for (int dt = 0; dt < 8; ++dt)
#pragma unroll
    for (int r = 0; r < 4; ++r) {
      const int qrow = qbase + g4 * 4 + r;
      O[((size_t)qrow * NH + head) * DD + dt * 16 + l15] = acc[dt][r];
    }

  if (l15 == 0) {
#pragma unroll
    for (int r = 0; r < 4; ++r) {
      const int qrow = qbase + g4 * 4 + r;
      Mo[(size_t)qrow * NH + head] = m[r];
      Lo[(size_t)qrow * NH + head] = lsum[r];
    }
  }
}

extern "C" void kernel_launch(void* const* d_in, const int* in_sizes, int n_in,
                              void* d_out, int out_size, void* d_ws, size_t ws_size,
                              hipStream_t stream) {
  const float* Q = (const float*)d_in[0];
  const float* K = (const float*)d_in[1];
  const float* V = (const float*)d_in[2];
  float* O  = (float*)d_out;
  float* Mo = O + (size_t)TT * NH * DD;
  float* Lo = Mo + (size_t)TT * NH;
  attn_fwd<<<dim3(64 * NKV), dim3(512), 0, stream>>>(Q, K, V, O, Mo, Lo);
}

// Round 3
// 100.215 us; speedup vs baseline: 1.7274x; 1.7274x over previous
//
#include <hip/hip_runtime.h>
#include <hip/hip_bf16.h>

#define TT  2048
#define NH  32
#define NKV 8
#define DD  128
#define KVB 64          // keys per LDS tile
#define KSTR 136        // K row stride in bf16: 272B
#define VSTR 72         // Vt row stride in bf16: 144B
#define PSTR 72         // P row stride in bf16

typedef __attribute__((ext_vector_type(8))) short  short8;
typedef __attribute__((ext_vector_type(4))) float  f32x4;

static __device__ __forceinline__ short f2bf(float x) {
  __bf16 b = (__bf16)x;                 // RNE f32->bf16
  return __builtin_bit_cast(short, b);
}
static __device__ __forceinline__ short8 cvt8(f32x4 a, f32x4 b) {
  short8 r;
  r[0]=f2bf(a[0]); r[1]=f2bf(a[1]); r[2]=f2bf(a[2]); r[3]=f2bf(a[3]);
  r[4]=f2bf(b[0]); r[5]=f2bf(b[1]); r[6]=f2bf(b[2]); r[7]=f2bf(b[3]);
  return r;
}

// Block = one kv-head x 32 Q-rows x 4 GQA heads. 8 waves.
// Split-phase async staging (spill-free T14):
//   - Kb is LDS double-buffered. K(t+1) issued at top of tile t, committed
//     into Kb[(t+1)&1] right after QK^T(t) (other buffer -> no barrier).
//     kreg in flight only across QK^T.
//   - Vt single-buffered. V(t+1) issued after softmax(t), committed at top
//     of tile t+1 (after barrier A). vreg in flight only across PV.
// => only one 16-reg in-flight set live at a time; peak live ~110 < 128
//    (the __launch_bounds__(512,4) unified VGPR+AGPR cap). No scratch.
// MFMA 16x16x32 bf16. A-frag: lane holds A[row=l&15][k=8*(l>>4)+i].
// B-frag: lane holds B[k=8*(l>>4)+i][col=l&15].
// C/D:    lane holds C[row=(l>>4)*4+r][col=l&15].
__global__ __launch_bounds__(512, 4) void attn_fwd(
    const float* __restrict__ Q, const float* __restrict__ K,
    const float* __restrict__ V, float* __restrict__ O,
    float* __restrict__ Mo, float* __restrict__ Lo)
{
  __shared__ __align__(16) short Kb[2][KVB][KSTR];  // K[j][d], bf16, dbuf
  __shared__ __align__(16) short Vt[DD][VSTR];      // V transposed: Vt[d][j]
  __shared__ __align__(16) short Pl[8][16][PSTR];   // per-wave P transpose buf

  const int bid  = blockIdx.x;
  const int kvh  = bid & (NKV - 1);          // kvh == XCD id under round-robin
  const int jj   = bid >> 3;                 // 0..63
  // balanced pairing: blocks c and c+256 land on the same CU (2 blocks/CU,
  // whole grid resident). Pair heavy (q32=63-jj) with light (q32=jj-32).
  const int q32  = (jj < 32) ? (63 - jj) : (jj - 32);
  const int wv   = threadIdx.x >> 6;         // 0..7
  const int lane = threadIdx.x & 63;
  const int l15  = lane & 15;
  const int g4   = lane >> 4;
  const int head = kvh * 4 + (wv & 3);
  const int qbase = q32 * 32 + (wv >> 2) * 16;

  // K staging: row = tid>>3 (coalesced 512B runs), 16-col seg = tid&7
  const int krow = threadIdx.x >> 3;
  const int kseg = threadIdx.x & 7;
  // V staging: row = lane, d-seg = wv*16 (per-wave-uniform d -> conflict-free scatter)
  const int vrow = lane;
  const int vd0  = wv * 16;

  // ---- Q fragments: lane holds Q[qbase+(l&15)][32*ks + 8*g4 + i] ----
  short8 aq[4];
  {
    const float* qp = Q + ((size_t)(qbase + l15) * NH + head) * DD;
#pragma unroll
    for (int ks = 0; ks < 4; ++ks) {
      const float* p = qp + ks * 32 + g4 * 8;
      aq[ks] = cvt8(*reinterpret_cast<const f32x4*>(p),
                    *reinterpret_cast<const f32x4*>(p + 4));
    }
  }

  f32x4 acc[8];
#pragma unroll
  for (int i = 0; i < 8; ++i) acc[i] = (f32x4)0.0f;
  float m[4], lsum[4];
#pragma unroll
  for (int r = 0; r < 4; ++r) { m[r] = -INFINITY; lsum[r] = 0.0f; }

  // ceil((q32*32+32)/64): same for both row-groups
  const int ntiles = (q32 * 32 + 95) >> 6;

  const size_t TSTEP = (size_t)KVB * NKV * DD;
  const float* kp = K + ((size_t)krow * NKV + kvh) * DD + kseg * 16;
  const float* vp = V + ((size_t)vrow * NKV + kvh) * DD + vd0;

  f32x4 kreg[4], vreg[4];
  // ---- prologue: issue K0+V0; commit K0 into Kb[0] (kreg dies here) ----
#pragma unroll
  for (int c = 0; c < 4; ++c) {
    kreg[c] = *reinterpret_cast<const f32x4*>(kp + c * 4);
    vreg[c] = *reinterpret_cast<const f32x4*>(vp + c * 4);
  }
  kp += TSTEP; vp += TSTEP;
  *reinterpret_cast<short8*>(&Kb[0][krow][kseg * 16])     = cvt8(kreg[0], kreg[1]);
  *reinterpret_cast<short8*>(&Kb[0][krow][kseg * 16 + 8]) = cvt8(kreg[2], kreg[3]);

  for (int jt = 0; jt < ntiles; ++jt) {
    const int j0 = jt << 6;
    const bool more = (jt + 1 < ntiles);

    __syncthreads();   // bar A: everyone done PV(jt-1); Kb[jt&1] commit visible

    // ---- commit V(jt) (loads issued one phase ago; vreg dies) ----
#pragma unroll
    for (int c = 0; c < 4; ++c)
#pragma unroll
      for (int i = 0; i < 4; ++i)
        Vt[vd0 + c * 4 + i][vrow] = f2bf(vreg[c][i]);

    // ---- issue K(jt+1): in flight across QK^T only ----
    if (more) {
#pragma unroll
      for (int c = 0; c < 4; ++c)
        kreg[c] = *reinterpret_cast<const f32x4*>(kp + c * 4);
      kp += TSTEP;
    }

    // ---- QK^T: S[16 x 64] as four 16-col C/D frags ----
    f32x4 s[4];
#pragma unroll
    for (int c = 0; c < 4; ++c) s[c] = (f32x4)0.0f;
    __builtin_amdgcn_s_setprio(1);
#pragma unroll
    for (int c = 0; c < 4; ++c) {
      const short* kr = &Kb[jt & 1][c * 16 + l15][g4 * 8];
#pragma unroll
      for (int ks = 0; ks < 4; ++ks) {
        short8 kb = *reinterpret_cast<const short8*>(kr + ks * 32);
        s[c] = __builtin_amdgcn_mfma_f32_16x16x32_bf16(aq[ks], kb, s[c], 0, 0, 0);
      }
    }
    __builtin_amdgcn_s_setprio(0);

    // ---- commit K(jt+1) into the other buffer (no barrier needed; kreg dies) ----
    if (more) {
      *reinterpret_cast<short8*>(&Kb[(jt + 1) & 1][krow][kseg * 16]) =
          cvt8(kreg[0], kreg[1]);
      *reinterpret_cast<short8*>(&Kb[(jt + 1) & 1][krow][kseg * 16 + 8]) =
          cvt8(kreg[2], kreg[3]);
    }

    // ---- causal mask: only the last tile can cross the diagonal ----
    if (jt == ntiles - 1) {
#pragma unroll
      for (int c = 0; c < 4; ++c)
#pragma unroll
        for (int r = 0; r < 4; ++r)
          if (j0 + c * 16 + l15 > qbase + g4 * 4 + r) s[c][r] = -1.0e10f;
    }

    // ---- online softmax over the 64-key tile ----
    float sc[4];
#pragma unroll
    for (int r = 0; r < 4; ++r) {
      float t = fmaxf(fmaxf(s[0][r], s[1][r]), fmaxf(s[2][r], s[3][r]));
      t = fmaxf(t, __shfl_xor(t, 1));
      t = fmaxf(t, __shfl_xor(t, 2));
      t = fmaxf(t, __shfl_xor(t, 4));
      t = fmaxf(t, __shfl_xor(t, 8));
      float mn = fmaxf(m[r], t);
      sc[r] = __expf(m[r] - mn);
      m[r] = mn;
      lsum[r] *= sc[r];
    }
#pragma unroll
    for (int c = 0; c < 4; ++c)
#pragma unroll
      for (int r = 0; r < 4; ++r) {
        float p = __expf(s[c][r] - m[r]);
        lsum[r] += p;
        Pl[wv][g4 * 4 + r][c * 16 + l15] = f2bf(p);
      }
    f32x4 sv; sv[0]=sc[0]; sv[1]=sc[1]; sv[2]=sc[2]; sv[3]=sc[3];
#pragma unroll
    for (int dt = 0; dt < 8; ++dt) acc[dt] = acc[dt] * sv;

    // ---- issue V(jt+1): in flight across PV only ----
    if (more) {
#pragma unroll
      for (int c = 0; c < 4; ++c)
        vreg[c] = *reinterpret_cast<const f32x4*>(vp + c * 4);
      vp += TSTEP;
    }

    __syncthreads();   // bar B: V(jt) committed by all waves before PV reads

    // ---- P @ V: K-dim = 64 keys, 8 d-tiles ----
    short8 pa0 = *reinterpret_cast<const short8*>(&Pl[wv][l15][g4 * 8]);
    short8 pa1 = *reinterpret_cast<const short8*>(&Pl[wv][l15][32 + g4 * 8]);
    __builtin_amdgcn_s_setprio(1);
#pragma unroll
    for (int dt = 0; dt < 8; ++dt) {
      short8 v0 = *reinterpret_cast<const short8*>(&Vt[dt * 16 + l15][g4 * 8]);
      short8 v1 = *reinterpret_cast<const short8*>(&Vt[dt * 16 + l15][32 + g4 * 8]);
      acc[dt] = __builtin_amdgcn_mfma_f32_16x16x32_bf16(pa0, v0, acc[dt], 0, 0, 0);
      acc[dt] = __builtin_amdgcn_mfma_f32_16x16x32_bf16(pa1, v1, acc[dt], 0, 0, 0);
    }
    __builtin_amdgcn_s_setprio(0);
  }

  // ---- epilogue ----
#pragma unroll
  for (int r = 0; r < 4; ++r) {
    float t = lsum[r];
    t += __shfl_xor(t, 1);
    t += __shfl_xor(t, 2);
    t += __shfl_xor(t, 4);
    t += __shfl_xor(t, 8);
    lsum[r] = t;
  }

#pragma unroll
  for (int dt = 0; dt < 8; ++dt)
#pragma unroll
    for (int r = 0; r < 4; ++r) {
      const int qrow = qbase + g4 * 4 + r;
      O[((size_t)qrow * NH + head) * DD + dt * 16 + l15] = acc[dt][r];
    }

  if (l15 == 0) {
#pragma unroll
    for (int r = 0; r < 4; ++r) {
      const int qrow = qbase + g4 * 4 + r;
      Mo[(size_t)qrow * NH + head] = m[r];
      Lo[(size_t)qrow * NH + head] = lsum[r];
    }
  }
}

extern "C" void kernel_launch(void* const* d_in, const int* in_sizes, int n_in,
                              void* d_out, int out_size, void* d_ws, size_t ws_size,
                              hipStream_t stream) {
  const float* Q = (const float*)d_in[0];
  const float* K = (const float*)d_in[1];
  const float* V = (const float*)d_in[2];
  float* O  = (float*)d_out;
  float* Mo = O + (size_t)TT * NH * DD;
  float* Lo = Mo + (size_t)TT * NH;
  attn_fwd<<<dim3(64 * NKV), dim3(512), 0, stream>>>(Q, K, V, O, Mo, Lo);
}